// Round 8
// baseline (477.940 us; speedup 1.0000x reference)
//
#include <hip/hip_runtime.h>

#define H 32
#define GPB 16  // 32-lane groups per 512-thread block (8 waves -> 2 waves/SIMD)

// tanh(x) = 1 - 2/(1 + exp2(x * 2*log2(e))); saturates correctly at +/-inf.
__device__ __forceinline__ float fast_tanh(float x) {
    float e = __builtin_amdgcn_exp2f(x * 2.8853900817779268f);
    float r = __builtin_amdgcn_rcpf(e + 1.0f);
    return fmaf(-2.0f, r, 1.0f);
}

// dpp mov via builtin => compiler inserts any required VALU->DPP hazard nops.
// bound_ctrl=1: out-of-row lanes read 0 (only matters for SHR patterns).
#define DPPMOV(x, ctrl) \
    __int_as_float(__builtin_amdgcn_update_dpp(0, __float_as_int(x), (ctrl), 0xf, 0xf, true))
#define QP0 0x00    // quad_perm:[0,0,0,0]
#define QP1 0x55    // quad_perm:[1,1,1,1]
#define QP2 0xAA    // quad_perm:[2,2,2,2]
#define QP3 0xFF    // quad_perm:[3,3,3,3]
#define RR4 0x124   // row_ror:4  (dst[i] = src[(i-4)&15] within 16-lane row)
#define SHR4 0x114  // row_shr:4
#define SHR8 0x118  // row_shr:8
#define SWZ_X16 0x401F  // ds_swizzle BitMode: lane ^ 16 (per 32-lane group)

// x-projection: 5 FMAs off broadcast-loaded onehot/reward.
#define XP(oh, rwc) fmaf((oh).x, wih0, fmaf((oh).y, wih1, fmaf((oh).z, wih2, \
                     fmaf((oh).w, wih3, fmaf((rwc), wih4, bias)))))

// One stage: broadcast quad elements b=0..3 of rr, FMA into the 4 accumulators.
#define STAGE(rr, W, j0) do { \
    q0 = DPPMOV(rr, QP0); q1 = DPPMOV(rr, QP1); \
    q2 = DPPMOV(rr, QP2); q3 = DPPMOV(rr, QP3); \
    a0 = fmaf(q0, W[j0+0], a0); a1 = fmaf(q1, W[j0+1], a1); \
    a2 = fmaf(q2, W[j0+2], a2); a3 = fmaf(q3, W[j0+3], a3); \
} while (0)

// Measured across R2/R4/R7: a single wave issues VALU at ~1 instr / 4 cyc
// (wall ~= instrs*4 regardless of deps). R5 proved 2 waves/SIMD co-issue;
// its DS-saturation penalty is gone now that the gather is DPP-only
// (1 ds_swizzle/step). So: 512-thr blocks, 1 block/CU -> 2 waves/SIMD;
// each wave's dep chain hides under the partner wave's execution.
__global__ __launch_bounds__(512, 2) void rnn_fused(
    const float* __restrict__ onehot,   // [B,T,4]
    const float* __restrict__ rewards,  // [B,T]
    const float* __restrict__ W_ih,     // [H,5]
    const float* __restrict__ W_hh,     // [H,H]
    const float* __restrict__ b_ih,     // [H]
    const float* __restrict__ b_hh,     // [H]
    const float* __restrict__ W_ro,     // [4,H]
    const float* __restrict__ b_ro,     // [4]
    float* __restrict__ out_logits,     // [B,T,4]
    float* __restrict__ out_hT,         // [B,H]
    int T)
{
    const int tid = threadIdx.x;
    const int u   = tid & 31;            // hidden unit owned by this lane
    const int b   = blockIdx.x * GPB + (tid >> 5);
    const bool wr = (u >= 12) && (u < 16);  // lanes 12..15 store logits 0..3

    // ---- pre-permuted W_hh so the rotating quad-broadcast sees the right k.
    // At stage s (after s row_ror:4), quad-broadcast b delivers
    //   h[(u&16) + ((4*((u>>2)&3) + b - 4*s) & 15)]   (own half)
    // and the same with base^16 for the swizzled half.
    float wown[16], woth[16];
    {
        const int base = u & 16;
        const int rb   = 4 * ((u >> 2) & 3);
        #pragma unroll
        for (int j = 0; j < 16; ++j) {
            const int s = j >> 2, bq = j & 3;
            const int kin = (rb + bq - 4 * s) & 15;
            wown[j] = W_hh[u * H + base + kin];
            woth[j] = W_hh[u * H + (base ^ 16) + kin];
        }
    }
    const float wih0 = W_ih[u*5+0], wih1 = W_ih[u*5+1], wih2 = W_ih[u*5+2],
                wih3 = W_ih[u*5+3], wih4 = W_ih[u*5+4];
    const float bias = b_ih[u] + b_hh[u];
    // readout: lane u covers row r=u&3, columns = its quad and the twin quad.
    const float4 wroq  = *(const float4*)(W_ro + (u & 3) * H + (u & ~3));
    const float4 wroq2 = *(const float4*)(W_ro + (u & 3) * H + ((u & ~3) ^ 16));
    const float broz = b_ro[u & 3];

    const float* oh_ptr = onehot  + (size_t)b * T * 4;
    const float* rw_ptr = rewards + (size_t)b * T;
    float*       lg_ptr = out_logits + (size_t)b * T * 4;

    // ---- two input-register banks so prefetch never clobbers live operands
    float4 oh0, oh1, oh2, oh3, rwv;
    float4 qh0, qh1, qh2, qh3, qrw;
    auto loadX = [&](int t) {
        oh0 = *(const float4*)(oh_ptr + (size_t)t * 4);
        oh1 = *(const float4*)(oh_ptr + (size_t)(t + 1) * 4);
        oh2 = *(const float4*)(oh_ptr + (size_t)(t + 2) * 4);
        oh3 = *(const float4*)(oh_ptr + (size_t)(t + 3) * 4);
        rwv = *(const float4*)(rw_ptr + t);
    };
    auto loadY = [&](int t) {
        qh0 = *(const float4*)(oh_ptr + (size_t)t * 4);
        qh1 = *(const float4*)(oh_ptr + (size_t)(t + 1) * 4);
        qh2 = *(const float4*)(oh_ptr + (size_t)(t + 2) * 4);
        qh3 = *(const float4*)(oh_ptr + (size_t)(t + 3) * 4);
        qrw = *(const float4*)(rw_ptr + t);
    };

    float hj;  // running hidden state h^{t}

    // One step: consumes hj = h^{t-1}, produces hj = h^{t}; also emits
    // logits_{t-1} (readout reuses the stage-0 broadcasts of h^{t-1}).
    auto step = [&](const float4& oh, float rwc, int emit_t) {
        const float h0 = hj;
        const int hsb = __builtin_amdgcn_ds_swizzle(__float_as_int(h0), SWZ_X16);
        float a0 = XP(oh, rwc), a1 = 0.f, a2 = 0.f, a3 = 0.f;
        float q0, q1, q2, q3;
        // own 16-half (4 stages, rotating by 4 lanes within the 16-row)
        STAGE(h0, wown, 0);
        float pr = q0 * wroq.x;                  // readout row partials
        pr = fmaf(q1, wroq.y, pr);
        pr = fmaf(q2, wroq.z, pr);
        pr = fmaf(q3, wroq.w, pr);
        float r = DPPMOV(h0, RR4);
        STAGE(r, wown, 4);
        r = DPPMOV(r, RR4);
        STAGE(r, wown, 8);
        r = DPPMOV(r, RR4);
        STAGE(r, wown, 12);
        // other 16-half (swizzle latency hidden under the work above)
        const float hs = __int_as_float(hsb);
        STAGE(hs, woth, 0);
        pr = fmaf(q0, wroq2.x, pr);
        pr = fmaf(q1, wroq2.y, pr);
        pr = fmaf(q2, wroq2.z, pr);
        pr = fmaf(q3, wroq2.w, pr);
        r = DPPMOV(hs, RR4);
        STAGE(r, woth, 4);
        r = DPPMOV(r, RR4);
        STAGE(r, woth, 8);
        r = DPPMOV(r, RR4);
        STAGE(r, woth, 12);
        // readout finish: reduce quad-partials down the 16-row; lanes 12..15
        // hold logits 0..3 of this 32-group (16B coalesced store).
        float t1 = pr + DPPMOV(pr, SHR4);
        float t2 = t1 + DPPMOV(t1, SHR8);
        if (wr) lg_ptr[(size_t)emit_t * 4 + (u & 3)] = t2 + broz;
        hj = fast_tanh((a0 + a1) + (a2 + a3));
    };

    // ---- prologue ----
    loadX(0);
    loadY(4);
    hj = fast_tanh(XP(oh0, rwv.x));      // t = 0 (h^{-1} = 0: mat-vec vanishes)
    step(oh1, rwv.y, 0);                 // t = 1, emits logits_0
    step(oh2, rwv.z, 1);
    step(oh3, rwv.w, 2);
    loadX(8);
    step(qh0, qrw.x, 3);                 // t = 4..7
    step(qh1, qrw.y, 4);
    step(qh2, qrw.z, 5);
    step(qh3, qrw.w, 6);
    loadY(12);

    // ---- steady state: 8 steps / iteration ----
    for (int tb = 8; tb < T; tb += 8) {
        step(oh0, rwv.x, tb - 1);
        step(oh1, rwv.y, tb + 0);
        step(oh2, rwv.z, tb + 1);
        step(oh3, rwv.w, tb + 2);
        if (tb + 8 < T) loadX(tb + 8);
        step(qh0, qrw.x, tb + 3);
        step(qh1, qrw.y, tb + 4);
        step(qh2, qrw.z, tb + 5);
        step(qh3, qrw.w, tb + 6);
        if (tb + 12 < T) loadY(tb + 12);
    }

    // ---- tail: logits_{T-1} from h^{T-1} ----
    {
        const int hsb = __builtin_amdgcn_ds_swizzle(__float_as_int(hj), SWZ_X16);
        float q0 = DPPMOV(hj, QP0), q1 = DPPMOV(hj, QP1),
              q2 = DPPMOV(hj, QP2), q3 = DPPMOV(hj, QP3);
        float pr = q0 * wroq.x;
        pr = fmaf(q1, wroq.y, pr);
        pr = fmaf(q2, wroq.z, pr);
        pr = fmaf(q3, wroq.w, pr);
        const float hs = __int_as_float(hsb);
        q0 = DPPMOV(hs, QP0); q1 = DPPMOV(hs, QP1);
        q2 = DPPMOV(hs, QP2); q3 = DPPMOV(hs, QP3);
        pr = fmaf(q0, wroq2.x, pr);
        pr = fmaf(q1, wroq2.y, pr);
        pr = fmaf(q2, wroq2.z, pr);
        pr = fmaf(q3, wroq2.w, pr);
        float t1 = pr + DPPMOV(pr, SHR4);
        float t2 = t1 + DPPMOV(t1, SHR8);
        if (wr) lg_ptr[(size_t)(T - 1) * 4 + (u & 3)] = t2 + broz;
    }
    out_hT[(size_t)b * H + u] = hj;      // h_T
}

extern "C" void kernel_launch(void* const* d_in, const int* in_sizes, int n_in,
                              void* d_out, int out_size, void* d_ws, size_t ws_size,
                              hipStream_t stream) {
    const float* onehot  = (const float*)d_in[0];
    const float* rewards = (const float*)d_in[1];
    const float* W_ih    = (const float*)d_in[2];
    const float* W_hh    = (const float*)d_in[3];
    const float* b_ih    = (const float*)d_in[4];
    const float* b_hh    = (const float*)d_in[5];
    const float* W_ro    = (const float*)d_in[6];
    const float* b_ro    = (const float*)d_in[7];

    const int T = 1024;                  // per setup_inputs()
    const int B = in_sizes[1] / T;       // in_sizes[1] = B*T

    float* out_logits = (float*)d_out;                        // [B,T,4]
    float* out_hT     = (float*)d_out + (size_t)B * T * 4;    // [B,H]

    dim3 block(512);                     // 8 waves/block, 1 block/CU -> 2 waves/SIMD
    dim3 grid(B / GPB);                  // = 128 blocks
    rnn_fused<<<grid, block, 0, stream>>>(onehot, rewards, W_ih, W_hh,
                                          b_ih, b_hh, W_ro, b_ro,
                                          out_logits, out_hT, T);
}

// Round 9
// 354.875 us; speedup vs baseline: 1.3468x; 1.3468x over previous
//
#include <hip/hip_runtime.h>

#define H 32
#define GPB 8   // 32-lane groups per 256-thread block

// tanh(x) = 1 - 2/(1 + exp2(x * 2*log2(e))); saturates correctly at +/-inf.
__device__ __forceinline__ float fast_tanh(float x) {
    float e = __builtin_amdgcn_exp2f(x * 2.8853900817779268f);
    float r = __builtin_amdgcn_rcpf(e + 1.0f);
    return fmaf(-2.0f, r, 1.0f);
}

#define SWZ_X16 0x401F  // ds_swizzle BitMode: lane ^ 16 (per 32-lane group)

// x-projection: 5 FMAs off broadcast-loaded onehot/reward.
#define XP(oh, rwc) fmaf((oh).x, wih0, fmaf((oh).y, wih1, fmaf((oh).z, wih2, \
                     fmaf((oh).w, wih3, fmaf((rwc), wih4, bias)))))

// Readout chain ops: fused broadcast-FMA off an old (>=4-instr) source.
// s_nop 1 at the chain head guards the only spot the scheduler could place a
// DPP read <2 cyc after the producer's VALU write.
#define ROMUL(prv, src, w) \
    asm("s_nop 1\n\t" \
        "v_mul_f32_dpp %0, %1, %2 quad_perm:[0,0,0,0] row_mask:0xf bank_mask:0xf" \
        : "=&v"(prv) : "v"(src), "v"(w))
#define ROFMA(prv, src, w, q) \
    asm("v_fmac_f32_dpp %0, %1, %2 quad_perm:[" #q "," #q "," #q "," #q "] row_mask:0xf bank_mask:0xf" \
        : "+v"(prv) : "v"(src), "v"(w))
// dst = src + (src shifted down SH lanes). Lanes whose shifted source is
// in-row are the only ones consumed (stores happen from lanes 12..15).
#define SHRADD(dst, src, SH) \
    asm("s_nop 1\n\t" \
        "v_mov_b32_dpp %0, %1 " SH " row_mask:0xf bank_mask:0xf\n\t" \
        "v_add_f32 %0, %1, %0" \
        : "=&v"(dst) : "v"(src))

// Own/other 16-half mat-vec: 16 fused v_fmac_f32_dpp + 3 row_ror:4, fixed
// schedule, every DPP source >=4 instrs old => zero wait-state hazards.
// FIRST: a1..a3 first-touched via v_mul (saves the 0-init movs). SECOND: all fmac.
#define MV_HALF_FIRST(h, W) \
    asm("s_nop 1\n\t" \
        "v_mov_b32_dpp %4, %7 row_ror:4 row_mask:0xf bank_mask:0xf\n\t" \
        "v_fmac_f32_dpp %0, %7, %8 quad_perm:[0,0,0,0] row_mask:0xf bank_mask:0xf\n\t" \
        "v_mul_f32_dpp %1, %7, %9 quad_perm:[1,1,1,1] row_mask:0xf bank_mask:0xf\n\t" \
        "v_mul_f32_dpp %2, %7, %10 quad_perm:[2,2,2,2] row_mask:0xf bank_mask:0xf\n\t" \
        "v_mul_f32_dpp %3, %7, %11 quad_perm:[3,3,3,3] row_mask:0xf bank_mask:0xf\n\t" \
        "v_mov_b32_dpp %5, %4 row_ror:4 row_mask:0xf bank_mask:0xf\n\t" \
        "v_fmac_f32_dpp %0, %4, %12 quad_perm:[0,0,0,0] row_mask:0xf bank_mask:0xf\n\t" \
        "v_fmac_f32_dpp %1, %4, %13 quad_perm:[1,1,1,1] row_mask:0xf bank_mask:0xf\n\t" \
        "v_fmac_f32_dpp %2, %4, %14 quad_perm:[2,2,2,2] row_mask:0xf bank_mask:0xf\n\t" \
        "v_fmac_f32_dpp %3, %4, %15 quad_perm:[3,3,3,3] row_mask:0xf bank_mask:0xf\n\t" \
        "v_mov_b32_dpp %6, %5 row_ror:4 row_mask:0xf bank_mask:0xf\n\t" \
        "v_fmac_f32_dpp %0, %5, %16 quad_perm:[0,0,0,0] row_mask:0xf bank_mask:0xf\n\t" \
        "v_fmac_f32_dpp %1, %5, %17 quad_perm:[1,1,1,1] row_mask:0xf bank_mask:0xf\n\t" \
        "v_fmac_f32_dpp %2, %5, %18 quad_perm:[2,2,2,2] row_mask:0xf bank_mask:0xf\n\t" \
        "v_fmac_f32_dpp %3, %5, %19 quad_perm:[3,3,3,3] row_mask:0xf bank_mask:0xf\n\t" \
        "v_fmac_f32_dpp %0, %6, %20 quad_perm:[0,0,0,0] row_mask:0xf bank_mask:0xf\n\t" \
        "v_fmac_f32_dpp %1, %6, %21 quad_perm:[1,1,1,1] row_mask:0xf bank_mask:0xf\n\t" \
        "v_fmac_f32_dpp %2, %6, %22 quad_perm:[2,2,2,2] row_mask:0xf bank_mask:0xf\n\t" \
        "v_fmac_f32_dpp %3, %6, %23 quad_perm:[3,3,3,3] row_mask:0xf bank_mask:0xf" \
        : "+v"(a0), "=&v"(a1), "=&v"(a2), "=&v"(a3), \
          "=&v"(r1), "=&v"(r2), "=&v"(r3) \
        : "v"(h), "v"(W[0]), "v"(W[1]), "v"(W[2]), "v"(W[3]), \
          "v"(W[4]), "v"(W[5]), "v"(W[6]), "v"(W[7]), \
          "v"(W[8]), "v"(W[9]), "v"(W[10]), "v"(W[11]), \
          "v"(W[12]), "v"(W[13]), "v"(W[14]), "v"(W[15]))

#define MV_HALF_SECOND(h, W) \
    asm("v_mov_b32_dpp %4, %7 row_ror:4 row_mask:0xf bank_mask:0xf\n\t" \
        "v_fmac_f32_dpp %0, %7, %8 quad_perm:[0,0,0,0] row_mask:0xf bank_mask:0xf\n\t" \
        "v_fmac_f32_dpp %1, %7, %9 quad_perm:[1,1,1,1] row_mask:0xf bank_mask:0xf\n\t" \
        "v_fmac_f32_dpp %2, %7, %10 quad_perm:[2,2,2,2] row_mask:0xf bank_mask:0xf\n\t" \
        "v_fmac_f32_dpp %3, %7, %11 quad_perm:[3,3,3,3] row_mask:0xf bank_mask:0xf\n\t" \
        "v_mov_b32_dpp %5, %4 row_ror:4 row_mask:0xf bank_mask:0xf\n\t" \
        "v_fmac_f32_dpp %0, %4, %12 quad_perm:[0,0,0,0] row_mask:0xf bank_mask:0xf\n\t" \
        "v_fmac_f32_dpp %1, %4, %13 quad_perm:[1,1,1,1] row_mask:0xf bank_mask:0xf\n\t" \
        "v_fmac_f32_dpp %2, %4, %14 quad_perm:[2,2,2,2] row_mask:0xf bank_mask:0xf\n\t" \
        "v_fmac_f32_dpp %3, %4, %15 quad_perm:[3,3,3,3] row_mask:0xf bank_mask:0xf\n\t" \
        "v_mov_b32_dpp %6, %5 row_ror:4 row_mask:0xf bank_mask:0xf\n\t" \
        "v_fmac_f32_dpp %0, %5, %16 quad_perm:[0,0,0,0] row_mask:0xf bank_mask:0xf\n\t" \
        "v_fmac_f32_dpp %1, %5, %17 quad_perm:[1,1,1,1] row_mask:0xf bank_mask:0xf\n\t" \
        "v_fmac_f32_dpp %2, %5, %18 quad_perm:[2,2,2,2] row_mask:0xf bank_mask:0xf\n\t" \
        "v_fmac_f32_dpp %3, %5, %19 quad_perm:[3,3,3,3] row_mask:0xf bank_mask:0xf\n\t" \
        "v_fmac_f32_dpp %0, %6, %20 quad_perm:[0,0,0,0] row_mask:0xf bank_mask:0xf\n\t" \
        "v_fmac_f32_dpp %1, %6, %21 quad_perm:[1,1,1,1] row_mask:0xf bank_mask:0xf\n\t" \
        "v_fmac_f32_dpp %2, %6, %22 quad_perm:[2,2,2,2] row_mask:0xf bank_mask:0xf\n\t" \
        "v_fmac_f32_dpp %3, %6, %23 quad_perm:[3,3,3,3] row_mask:0xf bank_mask:0xf" \
        : "+v"(a0), "+v"(a1), "+v"(a2), "+v"(a3), \
          "=&v"(r1), "=&v"(r2), "=&v"(r3) \
        : "v"(h), "v"(W[0]), "v"(W[1]), "v"(W[2]), "v"(W[3]), \
          "v"(W[4]), "v"(W[5]), "v"(W[6]), "v"(W[7]), \
          "v"(W[8]), "v"(W[9]), "v"(W[10]), "v"(W[11]), \
          "v"(W[12]), "v"(W[13]), "v"(W[14]), "v"(W[15]))

// Empirical law (R2/R4/R5/R7/R8): SIMD occupancy ~= 3.8-4 cyc per wave64
// instr for this mix; best config = full chip at 1 wave/SIMD; wall ~=
// T * instrs * 4 + exposed latency. This version cuts 97 -> ~69 instrs/step
// via fused v_fmac_f32_dpp and removes DPP wait-state nops by fixed-schedule
// asm (every DPP source >= 4 instrs old).
__global__ __launch_bounds__(256, 1) void rnn_fused(
    const float* __restrict__ onehot,   // [B,T,4]
    const float* __restrict__ rewards,  // [B,T]
    const float* __restrict__ W_ih,     // [H,5]
    const float* __restrict__ W_hh,     // [H,H]
    const float* __restrict__ b_ih,     // [H]
    const float* __restrict__ b_hh,     // [H]
    const float* __restrict__ W_ro,     // [4,H]
    const float* __restrict__ b_ro,     // [4]
    float* __restrict__ out_logits,     // [B,T,4]
    float* __restrict__ out_hT,         // [B,H]
    int T)
{
    const int tid = threadIdx.x;
    const int u   = tid & 31;            // hidden unit owned by this lane
    const int b   = blockIdx.x * GPB + (tid >> 5);
    const bool wr = (u >= 12) && (u < 16);  // lanes 12..15 store logits 0..3

    // ---- pre-permuted W_hh so the rotating quad-broadcast sees the right k.
    // At stage s (after s row_ror:4), quad-broadcast q delivers
    //   h[(u&16) + ((4*((u>>2)&3) + q - 4*s) & 15)]   (own half; ^16 for other)
    float wown[16], woth[16];
    {
        const int base = u & 16;
        const int rb   = 4 * ((u >> 2) & 3);
        #pragma unroll
        for (int j = 0; j < 16; ++j) {
            const int s = j >> 2, bq = j & 3;
            const int kin = (rb + bq - 4 * s) & 15;
            wown[j] = W_hh[u * H + base + kin];
            woth[j] = W_hh[u * H + (base ^ 16) + kin];
        }
    }
    const float wih0 = W_ih[u*5+0], wih1 = W_ih[u*5+1], wih2 = W_ih[u*5+2],
                wih3 = W_ih[u*5+3], wih4 = W_ih[u*5+4];
    const float bias = b_ih[u] + b_hh[u];
    // readout: lane u covers row r=u&3, columns = its quad and the twin quad.
    const float4 wroq  = *(const float4*)(W_ro + (u & 3) * H + (u & ~3));
    const float4 wroq2 = *(const float4*)(W_ro + (u & 3) * H + ((u & ~3) ^ 16));
    const float broz = b_ro[u & 3];

    const float* oh_ptr = onehot  + (size_t)b * T * 4;
    const float* rw_ptr = rewards + (size_t)b * T;
    float*       lg_ptr = out_logits + (size_t)b * T * 4;

    // ---- two input-register banks so prefetch never clobbers live operands
    float4 oh0, oh1, oh2, oh3, rwv;
    float4 qh0, qh1, qh2, qh3, qrw;
    auto loadX = [&](int t) {
        oh0 = *(const float4*)(oh_ptr + (size_t)t * 4);
        oh1 = *(const float4*)(oh_ptr + (size_t)(t + 1) * 4);
        oh2 = *(const float4*)(oh_ptr + (size_t)(t + 2) * 4);
        oh3 = *(const float4*)(oh_ptr + (size_t)(t + 3) * 4);
        rwv = *(const float4*)(rw_ptr + t);
    };
    auto loadY = [&](int t) {
        qh0 = *(const float4*)(oh_ptr + (size_t)t * 4);
        qh1 = *(const float4*)(oh_ptr + (size_t)(t + 1) * 4);
        qh2 = *(const float4*)(oh_ptr + (size_t)(t + 2) * 4);
        qh3 = *(const float4*)(oh_ptr + (size_t)(t + 3) * 4);
        qrw = *(const float4*)(rw_ptr + t);
    };

    float hj;  // running hidden state h^{t}

    // One step: consumes hj = h^{t-1}, produces hj = h^{t}; emits logits_{t-1}.
    // Summation order per accumulator/pr identical to R7 (bit-exact).
    auto step = [&](const float4& oh, float rwc, int emit_t) {
        const float h0 = hj;
        const int hsb = __builtin_amdgcn_ds_swizzle(__float_as_int(h0), SWZ_X16);
        float a0 = XP(oh, rwc), a1, a2, a3;
        float r1, r2, r3;
        MV_HALF_FIRST(h0, wown);             // own 16-half
        float pr;
        ROMUL(pr, h0, wroq.x);               // readout partials (own quads)
        ROFMA(pr, h0, wroq.y, 1);
        ROFMA(pr, h0, wroq.z, 2);
        ROFMA(pr, h0, wroq.w, 3);
        const float hs = __int_as_float(hsb);  // lgkmcnt-guarded at first use
        MV_HALF_SECOND(hs, woth);            // other 16-half
        ROFMA(pr, hs, wroq2.x, 0);
        ROFMA(pr, hs, wroq2.y, 1);
        ROFMA(pr, hs, wroq2.z, 2);
        ROFMA(pr, hs, wroq2.w, 3);
        float t1, t2;
        SHRADD(t1, pr, "row_shr:4");
        SHRADD(t2, t1, "row_shr:8");         // lane (8r'+12..15) holds row sums
        if (wr) lg_ptr[(size_t)emit_t * 4 + (u & 3)] = t2 + broz;
        hj = fast_tanh((a0 + a1) + (a2 + a3));
    };

    // ---- prologue ----
    loadX(0);
    loadY(4);
    hj = fast_tanh(XP(oh0, rwv.x));      // t = 0 (h^{-1} = 0: mat-vec vanishes)
    step(oh1, rwv.y, 0);                 // t = 1, emits logits_0
    step(oh2, rwv.z, 1);
    step(oh3, rwv.w, 2);
    loadX(8);
    step(qh0, qrw.x, 3);                 // t = 4..7
    step(qh1, qrw.y, 4);
    step(qh2, qrw.z, 5);
    step(qh3, qrw.w, 6);
    loadY(12);

    // ---- steady state: 8 steps / iteration ----
    for (int tb = 8; tb < T; tb += 8) {
        step(oh0, rwv.x, tb - 1);
        step(oh1, rwv.y, tb + 0);
        step(oh2, rwv.z, tb + 1);
        step(oh3, rwv.w, tb + 2);
        if (tb + 8 < T) loadX(tb + 8);
        step(qh0, qrw.x, tb + 3);
        step(qh1, qrw.y, tb + 4);
        step(qh2, qrw.z, tb + 5);
        step(qh3, qrw.w, tb + 6);
        if (tb + 12 < T) loadY(tb + 12);
    }

    // ---- tail: logits_{T-1} from h^{T-1} ----
    {
        const int hsb = __builtin_amdgcn_ds_swizzle(__float_as_int(hj), SWZ_X16);
        float pr;
        ROMUL(pr, hj, wroq.x);
        ROFMA(pr, hj, wroq.y, 1);
        ROFMA(pr, hj, wroq.z, 2);
        ROFMA(pr, hj, wroq.w, 3);
        const float hs = __int_as_float(hsb);
        ROFMA(pr, hs, wroq2.x, 0);
        ROFMA(pr, hs, wroq2.y, 1);
        ROFMA(pr, hs, wroq2.z, 2);
        ROFMA(pr, hs, wroq2.w, 3);
        float t1, t2;
        SHRADD(t1, pr, "row_shr:4");
        SHRADD(t2, t1, "row_shr:8");
        if (wr) lg_ptr[(size_t)(T - 1) * 4 + (u & 3)] = t2 + broz;
    }
    out_hT[(size_t)b * H + u] = hj;      // h_T
}

extern "C" void kernel_launch(void* const* d_in, const int* in_sizes, int n_in,
                              void* d_out, int out_size, void* d_ws, size_t ws_size,
                              hipStream_t stream) {
    const float* onehot  = (const float*)d_in[0];
    const float* rewards = (const float*)d_in[1];
    const float* W_ih    = (const float*)d_in[2];
    const float* W_hh    = (const float*)d_in[3];
    const float* b_ih    = (const float*)d_in[4];
    const float* b_hh    = (const float*)d_in[5];
    const float* W_ro    = (const float*)d_in[6];
    const float* b_ro    = (const float*)d_in[7];

    const int T = 1024;                  // per setup_inputs()
    const int B = in_sizes[1] / T;       // in_sizes[1] = B*T

    float* out_logits = (float*)d_out;                        // [B,T,4]
    float* out_hT     = (float*)d_out + (size_t)B * T * 4;    // [B,H]

    dim3 block(256);                     // 4 waves/block, 1024 waves total
    dim3 grid(B / GPB);                  // = 256 blocks -> 1 wave/SIMD chip-wide
    rnn_fused<<<grid, block, 0, stream>>>(onehot, rewards, W_ih, W_hh,
                                          b_ih, b_hh, W_ro, b_ro,
                                          out_logits, out_hT, T);
}